// Round 13
// baseline (225.524 us; speedup 1.0000x reference)
//
#include <hip/hip_runtime.h>

typedef __attribute__((ext_vector_type(8))) short short8;
typedef __attribute__((ext_vector_type(8))) _Float16 half8;
typedef __attribute__((ext_vector_type(4))) float f32x4;
typedef __attribute__((ext_vector_type(4))) unsigned short u16x4;
typedef __attribute__((ext_vector_type(4))) _Float16 half4;

#define NB 8
#define NQL 2048
#define NKL 2048
#define DD 512

static __device__ __forceinline__ void stage16(const void* g, void* l){
  __builtin_amdgcn_global_load_lds(
      (const __attribute__((address_space(1))) void*)g,
      (__attribute__((address_space(3))) void*)l, 16, 0, 0);
}

static __device__ __forceinline__ void barrier_lgkm(){
  asm volatile("s_waitcnt lgkmcnt(0)" ::: "memory");
  __builtin_amdgcn_s_barrier();
  asm volatile("" ::: "memory");
}

// ---------------- convert fp32 W -> fp16 single, all three in one launch ----------------
__global__ __launch_bounds__(256) void split3_k(
    const float* __restrict__ Wq, const float* __restrict__ Wk, const float* __restrict__ Wv,
    _Float16* __restrict__ w16q, _Float16* __restrict__ w16k, _Float16* __restrict__ w16v,
    int n4){
  const int z = blockIdx.y;
  const float* x = (z==0) ? Wq : (z==1) ? Wk : Wv;
  _Float16* o16 = (z==0) ? w16q : (z==1) ? w16k : w16v;
  int i = blockIdx.x*256 + threadIdx.x;
  if (i >= n4) return;
  f32x4 v = reinterpret_cast<const f32x4*>(x)[i];
  half4 h;
  #pragma unroll
  for (int j=0;j<4;j++) h[j] = (_Float16)v[j];
  reinterpret_cast<half4*>(o16)[i] = h;
}

// ---------------- fused projections: Y = X * W^T (128x128 tile, 2-pass fp16, dbuf) ----------------
// z=0: Q flat [16384][512], fp16 hi + fp16 lo
// z=1: K tiles [b][kt][32][512] fp16, col-group ^ (row&7)  (LDS-staged in attn)
// z=2: V tiles [b][kt][512][32] fp16, PLAIN layout          (reg-loaded in attn)
__global__ __launch_bounds__(256, 2) void proj2_k(
    const float* __restrict__ Xq, const float* __restrict__ Xk, const float* __restrict__ Xv,
    const _Float16* __restrict__ W16q, const _Float16* __restrict__ W16k, const _Float16* __restrict__ W16v,
    _Float16* __restrict__ Yqh, _Float16* __restrict__ Yql,
    _Float16* __restrict__ Ykt,
    _Float16* __restrict__ Yvt)
{
  __shared__ _Float16 AB[2][3][128][32];   // 48 KB: planes 0=Ah 1=Al 2=W

  const int z = blockIdx.z;
  const float*    X  = (z==0) ? Xq   : (z==1) ? Xk   : Xv;
  const _Float16* Wf = (z==0) ? W16q : (z==1) ? W16k : W16v;

  const int mbase = blockIdx.x * 128;
  const int nbase = blockIdx.y * 128;
  const int tid = threadIdx.x;
  const int w = tid >> 6, lane = tid & 63;
  const int l15 = lane & 15, l4 = lane >> 4;
  const int wr = w >> 1, wc = w & 1;

  const int arow = tid >> 1, ahalf = tid & 1;
  const int brow_l = w*16 + (lane>>2);
  const int bkg    = (lane & 3) ^ ((lane >> 3) & 3);

  f32x4 acc[4][4];
  #pragma unroll
  for (int m=0;m<4;m++)
    #pragma unroll
    for (int n=0;n<4;n++) acc[m][n] = (f32x4){0.f,0.f,0.f,0.f};

  f32x4 xa[4];
  {
    const f32x4* xp = reinterpret_cast<const f32x4*>(X + (size_t)(mbase+arow)*DD + ahalf*16);
    #pragma unroll
    for (int q=0;q<4;q++) xa[q] = xp[q];
  }
  {
    _Float16* lB = &AB[0][2][0][0] + w*512;
    #pragma unroll
    for (int r=0;r<2;r++){
      const size_t gh = (size_t)(nbase + r*64 + brow_l)*DD + bkg*8;
      stage16(Wf + gh, lB + r*2048);
    }
  }
  {
    asm volatile("s_waitcnt vmcnt(2)" ::: "memory");
    half8 h0,h1,l0,l1;
    #pragma unroll
    for (int j=0;j<4;j++){
      float v0 = xa[0][j], v1 = xa[1][j];
      h0[j] = (_Float16)v0; h0[4+j] = (_Float16)v1;
      l0[j] = (_Float16)(v0 - (float)h0[j]); l0[4+j] = (_Float16)(v1 - (float)h0[4+j]);
      float v2 = xa[2][j], v3 = xa[3][j];
      h1[j] = (_Float16)v2; h1[4+j] = (_Float16)v3;
      l1[j] = (_Float16)(v2 - (float)h1[j]); l1[4+j] = (_Float16)(v3 - (float)h1[4+j]);
    }
    const int sw = (arow>>1)&3;
    const int cg0 = (ahalf*2) ^ sw, cg1 = (ahalf*2+1) ^ sw;
    *reinterpret_cast<half8*>(&AB[0][0][arow][cg0*8]) = h0;
    *reinterpret_cast<half8*>(&AB[0][0][arow][cg1*8]) = h1;
    *reinterpret_cast<half8*>(&AB[0][1][arow][cg0*8]) = l0;
    *reinterpret_cast<half8*>(&AB[0][1][arow][cg1*8]) = l1;
  }

  const int asw = (l15>>1)&3;

  #pragma unroll 1
  for (int s=0; s<16; ++s){
    const int cur = s&1, nxt = cur^1;
    asm volatile("s_waitcnt vmcnt(0)" ::: "memory");
    barrier_lgkm();

    if (s < 15){
      const f32x4* xp = reinterpret_cast<const f32x4*>(X + (size_t)(mbase+arow)*DD + (s+1)*32 + ahalf*16);
      #pragma unroll
      for (int q=0;q<4;q++) xa[q] = xp[q];
      _Float16* lB = &AB[nxt][2][0][0] + w*512;
      #pragma unroll
      for (int r=0;r<2;r++){
        const size_t gh = (size_t)(nbase + r*64 + brow_l)*DD + (s+1)*32 + bkg*8;
        stage16(Wf + gh, lB + r*2048);
      }
    }

    half8 ah[4], al[4], wf[4];
    #pragma unroll
    for (int m=0;m<4;m++){
      const int rA = wr*64 + m*16 + l15;
      const int cg = (l4 ^ asw)*8;
      ah[m] = *reinterpret_cast<const half8*>(&AB[cur][0][rA][cg]);
      al[m] = *reinterpret_cast<const half8*>(&AB[cur][1][rA][cg]);
    }
    #pragma unroll
    for (int n=0;n<4;n++){
      const int rB = wc*64 + n*16 + l15;
      const int cg = (l4 ^ asw)*8;
      wf[n] = *reinterpret_cast<const half8*>(&AB[cur][2][rB][cg]);
    }
    #pragma unroll
    for (int m=0;m<4;m++)
      #pragma unroll
      for (int n=0;n<4;n++) acc[m][n] = __builtin_amdgcn_mfma_f32_16x16x32_f16(ah[m], wf[n], acc[m][n], 0,0,0);
    #pragma unroll
    for (int m=0;m<4;m++)
      #pragma unroll
      for (int n=0;n<4;n++) acc[m][n] = __builtin_amdgcn_mfma_f32_16x16x32_f16(al[m], wf[n], acc[m][n], 0,0,0);

    if (s < 15){
      asm volatile("s_waitcnt vmcnt(2)" ::: "memory");
      half8 h0,h1,l0,l1;
      #pragma unroll
      for (int j=0;j<4;j++){
        float v0 = xa[0][j], v1 = xa[1][j];
        h0[j] = (_Float16)v0; h0[4+j] = (_Float16)v1;
        l0[j] = (_Float16)(v0 - (float)h0[j]); l0[4+j] = (_Float16)(v1 - (float)h0[4+j]);
        float v2 = xa[2][j], v3 = xa[3][j];
        h1[j] = (_Float16)v2; h1[4+j] = (_Float16)v3;
        l1[j] = (_Float16)(v2 - (float)h1[j]); l1[4+j] = (_Float16)(v3 - (float)h1[4+j]);
      }
      const int sw = (arow>>1)&3;
      const int cg0 = (ahalf*2) ^ sw, cg1 = (ahalf*2+1) ^ sw;
      *reinterpret_cast<half8*>(&AB[nxt][0][arow][cg0*8]) = h0;
      *reinterpret_cast<half8*>(&AB[nxt][0][arow][cg1*8]) = h1;
      *reinterpret_cast<half8*>(&AB[nxt][1][arow][cg0*8]) = l0;
      *reinterpret_cast<half8*>(&AB[nxt][1][arow][cg1*8]) = l1;
    }
  }

  #pragma unroll
  for (int m=0;m<4;m++){
    #pragma unroll
    for (int n=0;n<4;n++){
      #pragma unroll
      for (int j=0;j<4;j++){
        const int row = mbase + wr*64 + m*16 + l4*4 + j;
        const int col = nbase + wc*64 + n*16 + l15;
        const float y = acc[m][n][j];
        if (z == 0){
          const _Float16 h = (_Float16)y;
          const _Float16 l = (_Float16)(y - (float)h);
          const size_t idx = (size_t)row*DD + col;
          Yqh[idx] = h; Yql[idx] = l;
        } else if (z == 1){
          const int bb = row >> 11, nn = row & 2047, kt = nn >> 5;
          const size_t tb = ((size_t)(bb*64 + kt)) << 14;
          const int kr = nn & 31, cg = col >> 3, ci = col & 7;
          const size_t idx = tb + ((size_t)kr)*512 + (size_t)((((cg ^ (kr & 7)) << 3)) | ci);
          Ykt[idx] = (_Float16)y;
        } else {
          const int bb = row >> 11, nn = row & 2047, kt = nn >> 5;
          const size_t tb = ((size_t)(bb*64 + kt)) << 14;
          const int kk = nn & 31;
          const size_t idx = tb + ((size_t)col)*32 + (size_t)kk;   // plain [dcol][k]
          Yvt[idx] = (_Float16)y;
        }
      }
    }
  }
}

// ---------------- fused flash attention: QB=32, 2 blocks/CU, V in registers ----------------
// 256 threads: waves 0-1 (QK, 16 q-rows each, 32 k-cols, in-reg softmax + defer-max),
// waves 2-3 (PV, all 32 rows x 256 d-cols; V reg-loaded direct from L2 tile).
// ONE barrier/step. K dbuf LDS (staged, full-step lead). P/sc parity dbuf.
// Cross-lane reduces via __shfl_xor (known-good; r12's permlane asm suspected bad codegen).
__global__ __launch_bounds__(256, 2) void attn_k(
    const _Float16* __restrict__ Qh, const _Float16* __restrict__ Ql,
    const _Float16* __restrict__ Kt,
    const _Float16* __restrict__ Vt,
    float* __restrict__ Out)
{
  __shared__ _Float16 K_lds[2][32][512];   // 64 KB dbuf (swizzled col-groups)
  __shared__ _Float16 P_s[2][32][40];      // 5 KB dbuf
  __shared__ float sc_s[2][32];
  __shared__ float l_s[32];

  const int bid = blockIdx.x;
  const int b  = bid & 7;
  const int qt = bid >> 3;                 // 0..63, 32 q-rows each
  const int tid = threadIdx.x;
  const int w = tid >> 6, lane = tid & 63;
  const int l15 = lane & 15, l4 = lane >> 4;
  const bool isQK = (w < 2);
  const int qw = w & 1;                    // QK: row-group. PV: col-half.

  const _Float16* gK = Kt + ((size_t)(b*64) << 14);
  const _Float16* gV = Vt + ((size_t)(b*64) << 14);
  const int goff  = w*512 + lane*8;        // 256 threads x 8 elems = 2048/round
  const int lbase = w*512;

  // role-dependent register file (128 VGPRs, statically indexed)
  f32x4 r[32];
  half8 vr[16];                            // PV only: V slice in regs (64 VGPRs)
  float m_old = -1e30f, lacc = 0.f;
  if (isQK){
    const size_t qoff = (size_t)(b*NQL + qt*32 + qw*16 + l15)*DD + l4*8;
    #pragma unroll
    for (int kc=0;kc<16;kc++){
      r[kc]    = __builtin_bit_cast(f32x4, *reinterpret_cast<const half8*>(Qh + qoff + kc*32));
      r[16+kc] = __builtin_bit_cast(f32x4, *reinterpret_cast<const half8*>(Ql + qoff + kc*32));
    }
  } else {
    #pragma unroll
    for (int i=0;i<32;i++) r[i] = (f32x4){0.f,0.f,0.f,0.f};
  }

  // prologue: stage K(0) -> kb[0]  (8 rounds x 2048 elems)
  {
    _Float16* lK = &K_lds[0][0][0];
    #pragma unroll
    for (int q=0;q<8;q++) stage16(gK + q*2048 + goff, lK + q*2048 + lbase);
  }

  const int kx = l15 & 7;
  const int row_i = qw*16 + l15;           // QK lane's q-row (local, 0..31)
  const int vcol = qw*256 + l15;           // PV lane's base col

  #pragma unroll 1
  for (int kt=0; kt<64; ++kt){
    const int par = kt & 1;
    asm volatile("s_waitcnt vmcnt(0)" ::: "memory");  // K(t) staged; (PV) V(t-1) in regs
    barrier_lgkm();                                   // + P(t-1)/sc(t-1) visible

    // stage K(t+1) -> kb[par^1]
    if (kt < 63){
      const _Float16* g = gK + ((size_t)(kt+1) << 14);
      _Float16* lK = &K_lds[par^1][0][0];
      #pragma unroll
      for (int q=0;q<8;q++) stage16(g + q*2048 + goff, lK + q*2048 + lbase);
    }

    if (isQK){
      // ---- S(t): two col-frags, 2-pass fp16 ----
      f32x4 s0h = (f32x4){0.f,0.f,0.f,0.f}, s0l = (f32x4){0.f,0.f,0.f,0.f};
      f32x4 s1h = (f32x4){0.f,0.f,0.f,0.f}, s1l = (f32x4){0.f,0.f,0.f,0.f};
      __builtin_amdgcn_s_setprio(1);
      #pragma unroll
      for (int kc=0;kc<16;kc++){
        const int cg = ((kc*4 + l4) ^ kx) << 3;
        const half8 kf0 = *reinterpret_cast<const half8*>(&K_lds[par][l15][cg]);
        const half8 kf1 = *reinterpret_cast<const half8*>(&K_lds[par][16+l15][cg]);
        const half8 qh = __builtin_bit_cast(half8, r[kc]);
        const half8 ql = __builtin_bit_cast(half8, r[16+kc]);
        s0h = __builtin_amdgcn_mfma_f32_16x16x32_f16(kf0, qh, s0h, 0,0,0);
        s0l = __builtin_amdgcn_mfma_f32_16x16x32_f16(kf0, ql, s0l, 0,0,0);
        s1h = __builtin_amdgcn_mfma_f32_16x16x32_f16(kf1, qh, s1h, 0,0,0);
        s1l = __builtin_amdgcn_mfma_f32_16x16x32_f16(kf1, ql, s1l, 0,0,0);
      }
      __builtin_amdgcn_s_setprio(0);
      const f32x4 sv0 = s0h + s0l;
      const f32x4 sv1 = s1h + s1l;

      // ---- softmax: speculative exp(m_old) overlapped with shfl max-reduce ----
      float mw = fmaxf(fmaxf(fmaxf(sv0[0],sv0[1]), fmaxf(sv0[2],sv0[3])),
                       fmaxf(fmaxf(sv1[0],sv1[1]), fmaxf(sv1[2],sv1[3])));
      float p0 = __expf(sv0[0]-m_old), p1 = __expf(sv0[1]-m_old);
      float p2 = __expf(sv0[2]-m_old), p3 = __expf(sv0[3]-m_old);
      float p4 = __expf(sv1[0]-m_old), p5 = __expf(sv1[1]-m_old);
      float p6 = __expf(sv1[2]-m_old), p7 = __expf(sv1[3]-m_old);
      mw = fmaxf(mw, __shfl_xor(mw, 16));
      mw = fmaxf(mw, __shfl_xor(mw, 32));
      float e_old = 1.0f;
      if (mw > m_old + 8.0f){
        e_old = __expf(m_old - mw);
        p0 = __expf(sv0[0]-mw); p1 = __expf(sv0[1]-mw);
        p2 = __expf(sv0[2]-mw); p3 = __expf(sv0[3]-mw);
        p4 = __expf(sv1[0]-mw); p5 = __expf(sv1[1]-mw);
        p6 = __expf(sv1[2]-mw); p7 = __expf(sv1[3]-mw);
        m_old = mw;
      }
      if (l4 == 0) sc_s[par][row_i] = e_old;
      uint2 hv;
      hv.x = (unsigned)__builtin_bit_cast(unsigned short,(_Float16)p0) |
             ((unsigned)__builtin_bit_cast(unsigned short,(_Float16)p1)<<16);
      hv.y = (unsigned)__builtin_bit_cast(unsigned short,(_Float16)p2) |
             ((unsigned)__builtin_bit_cast(unsigned short,(_Float16)p3)<<16);
      *reinterpret_cast<uint2*>(&P_s[par][row_i][l4*4]) = hv;
      uint2 hw;
      hw.x = (unsigned)__builtin_bit_cast(unsigned short,(_Float16)p4) |
             ((unsigned)__builtin_bit_cast(unsigned short,(_Float16)p5)<<16);
      hw.y = (unsigned)__builtin_bit_cast(unsigned short,(_Float16)p6) |
             ((unsigned)__builtin_bit_cast(unsigned short,(_Float16)p7)<<16);
      *reinterpret_cast<uint2*>(&P_s[par][row_i][16 + l4*4]) = hw;
      float ssum = (p0+p1)+(p2+p3)+((p4+p5)+(p6+p7));
      ssum += __shfl_xor(ssum, 16);
      ssum += __shfl_xor(ssum, 32);
      lacc = lacc*e_old + ssum;
    } else {
      const int pp = par^1;
      if (kt > 0){
        // ---- rescale O with sc(t-1) (sc==1 after defer-max warmup -> skipped) ----
        float scs[2][4];
        bool need = false;
        #pragma unroll
        for (int rg=0;rg<2;rg++)
          #pragma unroll
          for (int j=0;j<4;j++){
            scs[rg][j] = sc_s[pp][rg*16 + l4*4 + j];
            need = need || (scs[rg][j] < 0.999999f);
          }
        if (__any(need)){
          #pragma unroll
          for (int rg=0;rg<2;rg++)
            #pragma unroll
            for (int f=0;f<16;f++)
              #pragma unroll
              for (int j=0;j<4;j++) r[rg*16+f][j] *= scs[rg][j];
        }
        // ---- O += P(t-1) V(t-1): P from LDS (2 reads), V from regs ----
        const half8 pa0 = *reinterpret_cast<const half8*>(&P_s[pp][l15][l4*8]);
        const half8 pa1 = *reinterpret_cast<const half8*>(&P_s[pp][16+l15][l4*8]);
        __builtin_amdgcn_s_setprio(1);
        #pragma unroll
        for (int f=0;f<16;f++){
          r[f]    = __builtin_amdgcn_mfma_f32_16x16x32_f16(pa0, vr[f], r[f],    0,0,0);
          r[16+f] = __builtin_amdgcn_mfma_f32_16x16x32_f16(pa1, vr[f], r[16+f], 0,0,0);
        }
        __builtin_amdgcn_s_setprio(0);
      }
      // ---- issue V(t) reg loads (consumed next step; half-step L2 lead) ----
      {
        const _Float16* g = gV + ((size_t)kt << 14);
        #pragma unroll
        for (int f=0;f<16;f++){
          vr[f] = *reinterpret_cast<const half8*>(g + (size_t)(vcol + f*16)*32 + l4*8);
        }
      }
    }
  }

  // publish final l; drain V(63) + trailing stages
  if (isQK && l4 == 0) l_s[row_i] = lacc;
  asm volatile("s_waitcnt vmcnt(0)" ::: "memory");
  barrier_lgkm();

  if (!isQK){
    // rescale with sc(63) + PV(63) + normalize + store
    float scs[2][4];
    bool need = false;
    #pragma unroll
    for (int rg=0;rg<2;rg++)
      #pragma unroll
      for (int j=0;j<4;j++){
        scs[rg][j] = sc_s[1][rg*16 + l4*4 + j];
        need = need || (scs[rg][j] < 0.999999f);
      }
    if (__any(need)){
      #pragma unroll
      for (int rg=0;rg<2;rg++)
        #pragma unroll
        for (int f=0;f<16;f++)
          #pragma unroll
          for (int j=0;j<4;j++) r[rg*16+f][j] *= scs[rg][j];
    }
    const half8 pa0 = *reinterpret_cast<const half8*>(&P_s[1][l15][l4*8]);
    const half8 pa1 = *reinterpret_cast<const half8*>(&P_s[1][16+l15][l4*8]);
    #pragma unroll
    for (int f=0;f<16;f++){
      r[f]    = __builtin_amdgcn_mfma_f32_16x16x32_f16(pa0, vr[f], r[f],    0,0,0);
      r[16+f] = __builtin_amdgcn_mfma_f32_16x16x32_f16(pa1, vr[f], r[16+f], 0,0,0);
    }
    float inv[2][4];
    #pragma unroll
    for (int rg=0;rg<2;rg++)
      #pragma unroll
      for (int j=0;j<4;j++) inv[rg][j] = 1.0f / l_s[rg*16 + l4*4 + j];
    #pragma unroll
    for (int rg=0;rg<2;rg++){
      #pragma unroll
      for (int j=0;j<4;j++){
        const int row = rg*16 + l4*4 + j;
        const size_t obase = (size_t)(b*NQL + qt*32 + row)*DD;
        #pragma unroll
        for (int f=0;f<16;f++){
          Out[obase + qw*256 + f*16 + l15] = r[rg*16+f][j]*inv[rg][j];
        }
      }
    }
  }
}

extern "C" void kernel_launch(void* const* d_in, const int* in_sizes, int n_in,
                              void* d_out, int out_size, void* d_ws, size_t ws_size,
                              hipStream_t stream) {
  const float* query = (const float*)d_in[0];
  const float* key   = (const float*)d_in[1];
  const float* value = (const float*)d_in[2];
  const float* Wq    = (const float*)d_in[3];
  const float* Wk    = (const float*)d_in[4];
  const float* Wv    = (const float*)d_in[5];
  float* out = (float*)d_out;

  const size_t SB = (size_t)NB*NQL*DD;   // 8,388,608 elems
  const size_t WB = (size_t)DD*DD;

  _Float16* p = (_Float16*)d_ws;
  _Float16 *w16q = p, *w16k = p + WB, *w16v = p + 2*WB;
  _Float16* q0 = p + 3*WB;
  _Float16 *qh16 = q0,          *ql16 = q0 + SB;
  _Float16 *Kt16 = q0 + 2*SB;                 // [8][64][32][512] fp16 (swizzled)
  _Float16 *Vt16 = q0 + 3*SB;                 // [8][64][512][32] fp16 (plain)

  dim3 sg(256, 3);
  split3_k<<<sg, 256, 0, stream>>>(Wq, Wk, Wv, w16q, w16k, w16v, (int)(WB/4));

  dim3 pg(128, 4, 3);
  proj2_k<<<pg, 256, 0, stream>>>(query, key, value,
                                  w16q, w16k, w16v,
                                  qh16, ql16, Kt16, Vt16);

  attn_k<<<512, 256, 0, stream>>>(qh16, ql16, Kt16, Vt16, out);
}

// Round 14
// 173.316 us; speedup vs baseline: 1.3012x; 1.3012x over previous
//
#include <hip/hip_runtime.h>

typedef __attribute__((ext_vector_type(8))) short short8;
typedef __attribute__((ext_vector_type(8))) _Float16 half8;
typedef __attribute__((ext_vector_type(4))) float f32x4;
typedef __attribute__((ext_vector_type(4))) unsigned short u16x4;
typedef __attribute__((ext_vector_type(4))) _Float16 half4;

#define NB 8
#define NQL 2048
#define NKL 2048
#define DD 512

static __device__ __forceinline__ void stage16(const void* g, void* l){
  __builtin_amdgcn_global_load_lds(
      (const __attribute__((address_space(1))) void*)g,
      (__attribute__((address_space(3))) void*)l, 16, 0, 0);
}

static __device__ __forceinline__ void barrier_lgkm(){
  asm volatile("s_waitcnt lgkmcnt(0)" ::: "memory");
  __builtin_amdgcn_s_barrier();
  asm volatile("" ::: "memory");
}

// ---------------- convert fp32 W -> fp16 single, all three in one launch ----------------
__global__ __launch_bounds__(256) void split3_k(
    const float* __restrict__ Wq, const float* __restrict__ Wk, const float* __restrict__ Wv,
    _Float16* __restrict__ w16q, _Float16* __restrict__ w16k, _Float16* __restrict__ w16v,
    int n4){
  const int z = blockIdx.y;
  const float* x = (z==0) ? Wq : (z==1) ? Wk : Wv;
  _Float16* o16 = (z==0) ? w16q : (z==1) ? w16k : w16v;
  int i = blockIdx.x*256 + threadIdx.x;
  if (i >= n4) return;
  f32x4 v = reinterpret_cast<const f32x4*>(x)[i];
  half4 h;
  #pragma unroll
  for (int j=0;j<4;j++) h[j] = (_Float16)v[j];
  reinterpret_cast<half4*>(o16)[i] = h;
}

// ---------------- fused projections: Y = X * W^T (128x128 tile, single-pass fp16, dbuf) ----------------
// A = X fp16 (in-register convert), B = W fp16 (gload_lds staged).
// z=0: Q flat [16384][512] fp16
// z=1: K tiles [b][kt][32][512] fp16, col-group ^ (row&7)  (LDS-staged in attn)
// z=2: V tiles [b][kt][512][32] fp16, PLAIN layout          (reg-loaded in attn)
__global__ __launch_bounds__(256, 2) void proj2_k(
    const float* __restrict__ Xq, const float* __restrict__ Xk, const float* __restrict__ Xv,
    const _Float16* __restrict__ W16q, const _Float16* __restrict__ W16k, const _Float16* __restrict__ W16v,
    _Float16* __restrict__ Yq,
    _Float16* __restrict__ Ykt,
    _Float16* __restrict__ Yvt)
{
  __shared__ _Float16 AB[2][2][128][32];   // 32 KB: planes 0=A 1=W

  const int z = blockIdx.z;
  const float*    X  = (z==0) ? Xq   : (z==1) ? Xk   : Xv;
  const _Float16* Wf = (z==0) ? W16q : (z==1) ? W16k : W16v;

  const int mbase = blockIdx.x * 128;
  const int nbase = blockIdx.y * 128;
  const int tid = threadIdx.x;
  const int w = tid >> 6, lane = tid & 63;
  const int l15 = lane & 15, l4 = lane >> 4;
  const int wr = w >> 1, wc = w & 1;

  const int arow = tid >> 1, ahalf = tid & 1;
  const int brow_l = w*16 + (lane>>2);
  const int bkg    = (lane & 3) ^ ((lane >> 3) & 3);

  f32x4 acc[4][4];
  #pragma unroll
  for (int m=0;m<4;m++)
    #pragma unroll
    for (int n=0;n<4;n++) acc[m][n] = (f32x4){0.f,0.f,0.f,0.f};

  f32x4 xa[4];
  {
    const f32x4* xp = reinterpret_cast<const f32x4*>(X + (size_t)(mbase+arow)*DD + ahalf*16);
    #pragma unroll
    for (int q=0;q<4;q++) xa[q] = xp[q];
  }
  {
    _Float16* lB = &AB[0][1][0][0] + w*512;
    #pragma unroll
    for (int r=0;r<2;r++){
      const size_t gh = (size_t)(nbase + r*64 + brow_l)*DD + bkg*8;
      stage16(Wf + gh, lB + r*2048);
    }
  }
  {
    asm volatile("s_waitcnt vmcnt(2)" ::: "memory");   // A loads done, W stages outstanding
    half8 a0, a1;
    #pragma unroll
    for (int j=0;j<4;j++){
      a0[j] = (_Float16)xa[0][j]; a0[4+j] = (_Float16)xa[1][j];
      a1[j] = (_Float16)xa[2][j]; a1[4+j] = (_Float16)xa[3][j];
    }
    const int sw = (arow>>1)&3;
    const int cg0 = (ahalf*2) ^ sw, cg1 = (ahalf*2+1) ^ sw;
    *reinterpret_cast<half8*>(&AB[0][0][arow][cg0*8]) = a0;
    *reinterpret_cast<half8*>(&AB[0][0][arow][cg1*8]) = a1;
  }

  const int asw = (l15>>1)&3;

  #pragma unroll 1
  for (int s=0; s<16; ++s){
    const int cur = s&1, nxt = cur^1;
    asm volatile("s_waitcnt vmcnt(0)" ::: "memory");
    barrier_lgkm();

    if (s < 15){
      const f32x4* xp = reinterpret_cast<const f32x4*>(X + (size_t)(mbase+arow)*DD + (s+1)*32 + ahalf*16);
      #pragma unroll
      for (int q=0;q<4;q++) xa[q] = xp[q];
      _Float16* lB = &AB[nxt][1][0][0] + w*512;
      #pragma unroll
      for (int r=0;r<2;r++){
        const size_t gh = (size_t)(nbase + r*64 + brow_l)*DD + (s+1)*32 + bkg*8;
        stage16(Wf + gh, lB + r*2048);
      }
    }

    half8 ah[4], wf[4];
    #pragma unroll
    for (int m=0;m<4;m++){
      const int rA = wr*64 + m*16 + l15;
      const int cg = (l4 ^ asw)*8;
      ah[m] = *reinterpret_cast<const half8*>(&AB[cur][0][rA][cg]);
    }
    #pragma unroll
    for (int n=0;n<4;n++){
      const int rB = wc*64 + n*16 + l15;
      const int cg = (l4 ^ asw)*8;
      wf[n] = *reinterpret_cast<const half8*>(&AB[cur][1][rB][cg]);
    }
    #pragma unroll
    for (int m=0;m<4;m++)
      #pragma unroll
      for (int n=0;n<4;n++) acc[m][n] = __builtin_amdgcn_mfma_f32_16x16x32_f16(ah[m], wf[n], acc[m][n], 0,0,0);

    if (s < 15){
      asm volatile("s_waitcnt vmcnt(2)" ::: "memory");
      half8 a0, a1;
      #pragma unroll
      for (int j=0;j<4;j++){
        a0[j] = (_Float16)xa[0][j]; a0[4+j] = (_Float16)xa[1][j];
        a1[j] = (_Float16)xa[2][j]; a1[4+j] = (_Float16)xa[3][j];
      }
      const int sw = (arow>>1)&3;
      const int cg0 = (ahalf*2) ^ sw, cg1 = (ahalf*2+1) ^ sw;
      *reinterpret_cast<half8*>(&AB[nxt][0][arow][cg0*8]) = a0;
      *reinterpret_cast<half8*>(&AB[nxt][0][arow][cg1*8]) = a1;
    }
  }

  #pragma unroll
  for (int m=0;m<4;m++){
    #pragma unroll
    for (int n=0;n<4;n++){
      #pragma unroll
      for (int j=0;j<4;j++){
        const int row = mbase + wr*64 + m*16 + l4*4 + j;
        const int col = nbase + wc*64 + n*16 + l15;
        const float y = acc[m][n][j];
        if (z == 0){
          Yq[(size_t)row*DD + col] = (_Float16)y;
        } else if (z == 1){
          const int bb = row >> 11, nn = row & 2047, kt = nn >> 5;
          const size_t tb = ((size_t)(bb*64 + kt)) << 14;
          const int kr = nn & 31, cg = col >> 3, ci = col & 7;
          const size_t idx = tb + ((size_t)kr)*512 + (size_t)((((cg ^ (kr & 7)) << 3)) | ci);
          Ykt[idx] = (_Float16)y;
        } else {
          const int bb = row >> 11, nn = row & 2047, kt = nn >> 5;
          const size_t tb = ((size_t)(bb*64 + kt)) << 14;
          const int kk = nn & 31;
          const size_t idx = tb + ((size_t)col)*32 + (size_t)kk;   // plain [dcol][k]
          Yvt[idx] = (_Float16)y;
        }
      }
    }
  }
}

// ---------------- fused flash attention: QB=32, wave-specialized, single-pass fp16 QK ----------------
// 256 threads: waves 0-1 (QK, 16 q-rows each, 32 k-cols, in-reg softmax + defer-max),
// waves 2-3 (PV, all 32 rows x 256 d-cols; V reg-loaded direct from L2 tile).
// ONE barrier/step. K dbuf LDS (staged, full-step lead). P/sc parity dbuf.
__global__ __launch_bounds__(256, 2) void attn_k(
    const _Float16* __restrict__ Qf,
    const _Float16* __restrict__ Kt,
    const _Float16* __restrict__ Vt,
    float* __restrict__ Out)
{
  __shared__ _Float16 K_lds[2][32][512];   // 64 KB dbuf (swizzled col-groups)
  __shared__ _Float16 P_s[2][32][40];      // 5 KB dbuf
  __shared__ float sc_s[2][32];
  __shared__ float l_s[32];

  const int bid = blockIdx.x;
  const int b  = bid & 7;
  const int qt = bid >> 3;                 // 0..63, 32 q-rows each
  const int tid = threadIdx.x;
  const int w = tid >> 6, lane = tid & 63;
  const int l15 = lane & 15, l4 = lane >> 4;
  const bool isQK = (w < 2);
  const int qw = w & 1;                    // QK: row-group. PV: col-half.

  const _Float16* gK = Kt + ((size_t)(b*64) << 14);
  const _Float16* gV = Vt + ((size_t)(b*64) << 14);
  const int goff  = w*512 + lane*8;        // 256 threads x 8 elems = 2048/round
  const int lbase = w*512;

  // role-dependent register file (statically indexed)
  f32x4 r[32];                             // QK: r[0..15] = Q frags. PV: O accum.
  half8 vr[16];                            // PV only: V slice in regs
  float m_old = -1e30f, lacc = 0.f;
  if (isQK){
    const size_t qoff = (size_t)(b*NQL + qt*32 + qw*16 + l15)*DD + l4*8;
    #pragma unroll
    for (int kc=0;kc<16;kc++){
      r[kc] = __builtin_bit_cast(f32x4, *reinterpret_cast<const half8*>(Qf + qoff + kc*32));
    }
  } else {
    #pragma unroll
    for (int i=0;i<32;i++) r[i] = (f32x4){0.f,0.f,0.f,0.f};
  }

  // prologue: stage K(0) -> kb[0]  (8 rounds x 2048 elems)
  {
    _Float16* lK = &K_lds[0][0][0];
    #pragma unroll
    for (int q=0;q<8;q++) stage16(gK + q*2048 + goff, lK + q*2048 + lbase);
  }

  const int kx = l15 & 7;
  const int row_i = qw*16 + l15;           // QK lane's q-row (local, 0..31)
  const int vcol = qw*256 + l15;           // PV lane's base col

  #pragma unroll 1
  for (int kt=0; kt<64; ++kt){
    const int par = kt & 1;
    asm volatile("s_waitcnt vmcnt(0)" ::: "memory");  // K(t) staged; (PV) V(t-1) in regs
    barrier_lgkm();                                   // + P(t-1)/sc(t-1) visible

    // stage K(t+1) -> kb[par^1]
    if (kt < 63){
      const _Float16* g = gK + ((size_t)(kt+1) << 14);
      _Float16* lK = &K_lds[par^1][0][0];
      #pragma unroll
      for (int q=0;q<8;q++) stage16(g + q*2048 + goff, lK + q*2048 + lbase);
    }

    if (isQK){
      // ---- S(t): two col-frags, single-pass fp16 ----
      f32x4 s0 = (f32x4){0.f,0.f,0.f,0.f};
      f32x4 s1 = (f32x4){0.f,0.f,0.f,0.f};
      __builtin_amdgcn_s_setprio(1);
      #pragma unroll
      for (int kc=0;kc<16;kc++){
        const int cg = ((kc*4 + l4) ^ kx) << 3;
        const half8 kf0 = *reinterpret_cast<const half8*>(&K_lds[par][l15][cg]);
        const half8 kf1 = *reinterpret_cast<const half8*>(&K_lds[par][16+l15][cg]);
        const half8 q = __builtin_bit_cast(half8, r[kc]);
        s0 = __builtin_amdgcn_mfma_f32_16x16x32_f16(kf0, q, s0, 0,0,0);
        s1 = __builtin_amdgcn_mfma_f32_16x16x32_f16(kf1, q, s1, 0,0,0);
      }
      __builtin_amdgcn_s_setprio(0);
      const f32x4 sv0 = s0;
      const f32x4 sv1 = s1;

      // ---- softmax: speculative exp(m_old) overlapped with shfl max-reduce ----
      float mw = fmaxf(fmaxf(fmaxf(sv0[0],sv0[1]), fmaxf(sv0[2],sv0[3])),
                       fmaxf(fmaxf(sv1[0],sv1[1]), fmaxf(sv1[2],sv1[3])));
      float p0 = __expf(sv0[0]-m_old), p1 = __expf(sv0[1]-m_old);
      float p2 = __expf(sv0[2]-m_old), p3 = __expf(sv0[3]-m_old);
      float p4 = __expf(sv1[0]-m_old), p5 = __expf(sv1[1]-m_old);
      float p6 = __expf(sv1[2]-m_old), p7 = __expf(sv1[3]-m_old);
      mw = fmaxf(mw, __shfl_xor(mw, 16));
      mw = fmaxf(mw, __shfl_xor(mw, 32));
      float e_old = 1.0f;
      if (mw > m_old + 8.0f){
        e_old = __expf(m_old - mw);
        p0 = __expf(sv0[0]-mw); p1 = __expf(sv0[1]-mw);
        p2 = __expf(sv0[2]-mw); p3 = __expf(sv0[3]-mw);
        p4 = __expf(sv1[0]-mw); p5 = __expf(sv1[1]-mw);
        p6 = __expf(sv1[2]-mw); p7 = __expf(sv1[3]-mw);
        m_old = mw;
      }
      if (l4 == 0) sc_s[par][row_i] = e_old;
      uint2 hv;
      hv.x = (unsigned)__builtin_bit_cast(unsigned short,(_Float16)p0) |
             ((unsigned)__builtin_bit_cast(unsigned short,(_Float16)p1)<<16);
      hv.y = (unsigned)__builtin_bit_cast(unsigned short,(_Float16)p2) |
             ((unsigned)__builtin_bit_cast(unsigned short,(_Float16)p3)<<16);
      *reinterpret_cast<uint2*>(&P_s[par][row_i][l4*4]) = hv;
      uint2 hw;
      hw.x = (unsigned)__builtin_bit_cast(unsigned short,(_Float16)p4) |
             ((unsigned)__builtin_bit_cast(unsigned short,(_Float16)p5)<<16);
      hw.y = (unsigned)__builtin_bit_cast(unsigned short,(_Float16)p6) |
             ((unsigned)__builtin_bit_cast(unsigned short,(_Float16)p7)<<16);
      *reinterpret_cast<uint2*>(&P_s[par][row_i][16 + l4*4]) = hw;
      float ssum = (p0+p1)+(p2+p3)+((p4+p5)+(p6+p7));
      ssum += __shfl_xor(ssum, 16);
      ssum += __shfl_xor(ssum, 32);
      lacc = lacc*e_old + ssum;
    } else {
      const int pp = par^1;
      if (kt > 0){
        // ---- rescale O with sc(t-1) (sc==1 after defer-max warmup -> skipped) ----
        float scs[2][4];
        bool need = false;
        #pragma unroll
        for (int rg=0;rg<2;rg++)
          #pragma unroll
          for (int j=0;j<4;j++){
            scs[rg][j] = sc_s[pp][rg*16 + l4*4 + j];
            need = need || (scs[rg][j] < 0.999999f);
          }
        if (__any(need)){
          #pragma unroll
          for (int rg=0;rg<2;rg++)
            #pragma unroll
            for (int f=0;f<16;f++)
              #pragma unroll
              for (int j=0;j<4;j++) r[rg*16+f][j] *= scs[rg][j];
        }
        // ---- O += P(t-1) V(t-1): P from LDS (2 reads), V from regs ----
        const half8 pa0 = *reinterpret_cast<const half8*>(&P_s[pp][l15][l4*8]);
        const half8 pa1 = *reinterpret_cast<const half8*>(&P_s[pp][16+l15][l4*8]);
        __builtin_amdgcn_s_setprio(1);
        #pragma unroll
        for (int f=0;f<16;f++){
          r[f]    = __builtin_amdgcn_mfma_f32_16x16x32_f16(pa0, vr[f], r[f],    0,0,0);
          r[16+f] = __builtin_amdgcn_mfma_f32_16x16x32_f16(pa1, vr[f], r[16+f], 0,0,0);
        }
        __builtin_amdgcn_s_setprio(0);
      }
      // ---- issue V(t) reg loads (consumed next step; half-step L2 lead) ----
      {
        const _Float16* g = gV + ((size_t)kt << 14);
        #pragma unroll
        for (int f=0;f<16;f++){
          vr[f] = *reinterpret_cast<const half8*>(g + (size_t)(vcol + f*16)*32 + l4*8);
        }
      }
    }
  }

  // publish final l; drain V(63) + trailing stages
  if (isQK && l4 == 0) l_s[row_i] = lacc;
  asm volatile("s_waitcnt vmcnt(0)" ::: "memory");
  barrier_lgkm();

  if (!isQK){
    // rescale with sc(63) + PV(63) + normalize + store
    float scs[2][4];
    bool need = false;
    #pragma unroll
    for (int rg=0;rg<2;rg++)
      #pragma unroll
      for (int j=0;j<4;j++){
        scs[rg][j] = sc_s[1][rg*16 + l4*4 + j];
        need = need || (scs[rg][j] < 0.999999f);
      }
    if (__any(need)){
      #pragma unroll
      for (int rg=0;rg<2;rg++)
        #pragma unroll
        for (int f=0;f<16;f++)
          #pragma unroll
          for (int j=0;j<4;j++) r[rg*16+f][j] *= scs[rg][j];
    }
    const half8 pa0 = *reinterpret_cast<const half8*>(&P_s[1][l15][l4*8]);
    const half8 pa1 = *reinterpret_cast<const half8*>(&P_s[1][16+l15][l4*8]);
    #pragma unroll
    for (int f=0;f<16;f++){
      r[f]    = __builtin_amdgcn_mfma_f32_16x16x32_f16(pa0, vr[f], r[f],    0,0,0);
      r[16+f] = __builtin_amdgcn_mfma_f32_16x16x32_f16(pa1, vr[f], r[16+f], 0,0,0);
    }
    float inv[2][4];
    #pragma unroll
    for (int rg=0;rg<2;rg++)
      #pragma unroll
      for (int j=0;j<4;j++) inv[rg][j] = 1.0f / l_s[rg*16 + l4*4 + j];
    #pragma unroll
    for (int rg=0;rg<2;rg++){
      #pragma unroll
      for (int j=0;j<4;j++){
        const int row = rg*16 + l4*4 + j;
        const size_t obase = (size_t)(b*NQL + qt*32 + row)*DD;
        #pragma unroll
        for (int f=0;f<16;f++){
          Out[obase + qw*256 + f*16 + l15] = r[rg*16+f][j]*inv[rg][j];
        }
      }
    }
  }
}

extern "C" void kernel_launch(void* const* d_in, const int* in_sizes, int n_in,
                              void* d_out, int out_size, void* d_ws, size_t ws_size,
                              hipStream_t stream) {
  const float* query = (const float*)d_in[0];
  const float* key   = (const float*)d_in[1];
  const float* value = (const float*)d_in[2];
  const float* Wq    = (const float*)d_in[3];
  const float* Wk    = (const float*)d_in[4];
  const float* Wv    = (const float*)d_in[5];
  float* out = (float*)d_out;

  const size_t SB = (size_t)NB*NQL*DD;   // 8,388,608 elems
  const size_t WB = (size_t)DD*DD;

  _Float16* p = (_Float16*)d_ws;
  _Float16 *w16q = p, *w16k = p + WB, *w16v = p + 2*WB;
  _Float16* q0 = p + 3*WB;
  _Float16 *q16  = q0;                        // [16384][512] fp16
  _Float16 *Kt16 = q0 + SB;                   // [8][64][32][512] fp16 (swizzled)
  _Float16 *Vt16 = q0 + 2*SB;                 // [8][64][512][32] fp16 (plain)

  dim3 sg(256, 3);
  split3_k<<<sg, 256, 0, stream>>>(Wq, Wk, Wv, w16q, w16k, w16v, (int)(WB/4));

  dim3 pg(128, 4, 3);
  proj2_k<<<pg, 256, 0, stream>>>(query, key, value,
                                  w16q, w16k, w16v,
                                  q16, Kt16, Vt16);

  attn_k<<<512, 256, 0, stream>>>(q16, Kt16, Vt16, out);
}